// Round 1
// baseline (190.912 us; speedup 1.0000x reference)
//
#include <hip/hip_runtime.h>
#include <math.h>

#define Bv 4
#define Nv 256
#define Cv 32
#define Mv 4
#define OUTv 64
#define MCv (Mv*Cv)      // 128

typedef _Float16 h8 __attribute__((ext_vector_type(8)));
typedef _Float16 h4 __attribute__((ext_vector_type(4)));
typedef float f4 __attribute__((ext_vector_type(4)));

// ---- static device scratch ----
__device__ __align__(16) float g_rs  [Bv * Nv * Cv];
__device__ __align__(16) float g_cs  [Bv * Nv * Cv];
__device__ __align__(16) float g_dgx [Bv * Nv * Cv];
__device__ __align__(16) float g_nb  [Bv * Nv * Mv];
__device__ __align__(16) float g_S1  [Bv * Nv * MCv];
__device__ __align__(16) float g_S2  [Bv * Nv * MCv];
__device__ __align__(16) float g_rcs2[Bv * MCv];        // atomic accum
__device__ __align__(16) float g_ds2 [Bv * MCv];        // atomic accum
__device__ __align__(16) float g_addv[Bv * Nv * OUTv];
__device__ __align__(16) _Float16 g_wfrag[8 * 4 * 64 * 8];   // 32 KB

// ---------------- K1: row/col/diag contractions, direction-split --------------
// Also absorbs the old k_wpackz: blocks bx >= 2*Nv (gated to blockIdx.y==0)
// pack w2d -> f16 fragment order / zero the atomic accumulators.
// bx < Nv : col-dir, n=bx: rs[n,c] = (1/N) sum_i x[i,n,c]; also dgx[n]
// bx >= Nv: row-dir, n=bx-Nv: cs[n,c] = (1/N) sum_j x[n,j,c]
__global__ __launch_bounds__(256) void k_contract1(const float* __restrict__ x,
                                                   const float* __restrict__ w2d) {
    int bx = blockIdx.x, b = blockIdx.y;
    int t = threadIdx.x;
    if (bx >= 2 * Nv) {
        if (b != 0) return;              // pack/zero work done once
        int r = bx - 2 * Nv;
        if (r == 8) {                    // zero rcs2/ds2 (atomic accumulators)
            if (t < 128) ((float4*)g_rcs2)[t] = {0.f,0.f,0.f,0.f};
            else         ((float4*)g_ds2)[t - 128] = {0.f,0.f,0.f,0.f};
            return;
        }
        int fi = r * 256 + t;
        int s = fi >> 8, q = (fi >> 6) & 3, lane = fi & 63;
        int k0 = s * 32 + ((lane >> 4) << 3);
        int o = q * 16 + (lane & 15);
        #pragma unroll
        for (int jj = 0; jj < 8; jj++)
            g_wfrag[fi * 8 + jj] = (_Float16)w2d[(size_t)(k0 + jj) * OUTv + o];
        return;
    }
    int c4 = t & 7, sub = t >> 3;   // 32 subs x 8 float4-cols
    const float4* xb4 = (const float4*)(x + (size_t)b * Nv * Nv * Cv);
    __shared__ float red[32][36];
    float4 acc = {0.f,0.f,0.f,0.f};
    if (bx < Nv) {
        int n = bx;
        for (int i = sub; i < Nv; i += 32) {
            float4 v = xb4[((size_t)i * Nv + n) * 8 + c4];
            acc.x += v.x; acc.y += v.y; acc.z += v.z; acc.w += v.w;
        }
        red[sub][c4*4+0] = acc.x; red[sub][c4*4+1] = acc.y;
        red[sub][c4*4+2] = acc.z; red[sub][c4*4+3] = acc.w;
        __syncthreads();
        if (t < 32) {
            float s = 0.f;
            #pragma unroll
            for (int k = 0; k < 32; k++) s += red[k][t];
            g_rs[(b * Nv + n) * Cv + t] = s * (1.0f / Nv);
        }
        if (t < 8) ((float4*)g_dgx)[(b * Nv + n) * 8 + t] = xb4[((size_t)n * Nv + n) * 8 + t];
    } else {
        int n = bx - Nv;
        for (int j = sub; j < Nv; j += 32) {
            float4 v = xb4[((size_t)n * Nv + j) * 8 + c4];
            acc.x += v.x; acc.y += v.y; acc.z += v.z; acc.w += v.w;
        }
        red[sub][c4*4+0] = acc.x; red[sub][c4*4+1] = acc.y;
        red[sub][c4*4+2] = acc.z; red[sub][c4*4+3] = acc.w;
        __syncthreads();
        if (t < 32) {
            float s = 0.f;
            #pragma unroll
            for (int k = 0; k < 32; k++) s += red[k][t];
            g_cs[(b * Nv + n) * Cv + t] = s * (1.0f / Nv);
        }
    }
}

// ---------------- K2: neighborhood linear + sigmoid ----------------
__global__ void k_neighb(const float* __restrict__ w1, const float* __restrict__ b1,
                         const float* __restrict__ w0, const float* __restrict__ b0) {
    int b = blockIdx.x, t = threadIdx.x;
    int c = t & 31, sub = t >> 5;
    float ar = 0.f, ad = 0.f;
    for (int n = sub; n < Nv; n += 8) {
        ar += g_rs[(b * Nv + n) * Cv + c];
        ad += g_dgx[(b * Nv + n) * Cv + c];
    }
    __shared__ float red[8][64];
    __shared__ float obj0[64];
    __shared__ float t0nb[4];
    red[sub][c] = ar;
    red[sub][32 + c] = ad;
    __syncthreads();
    if (t < 64) {
        float s = 0.f;
        #pragma unroll
        for (int k = 0; k < 8; k++) s += red[k][t];
        obj0[t] = s * (1.0f / Nv);
    }
    __syncthreads();
    if (t < 4) {
        float v = b0[t];
        for (int k = 0; k < 2 * Cv; k++) v += obj0[k] * w0[k * Mv + t];
        t0nb[t] = v;
    }
    __syncthreads();
    int n = t;
    float node[4];
    #pragma unroll
    for (int m = 0; m < 4; m++) node[m] = t0nb[m] + b1[m];
    for (int cc = 0; cc < Cv; cc++) {
        float r = g_rs[(b * Nv + n) * Cv + cc];
        float s = g_cs[(b * Nv + n) * Cv + cc];
        float d = g_dgx[(b * Nv + n) * Cv + cc];
        #pragma unroll
        for (int m = 0; m < 4; m++)
            node[m] += r * w1[cc * Mv + m] + s * w1[(Cv + cc) * Mv + m] + d * w1[(2 * Cv + cc) * Mv + m];
    }
    #pragma unroll
    for (int m = 0; m < 4; m++)
        g_nb[(b * Nv + n) * Mv + m] = 1.0f / (1.0f + expf(-node[m]));
}

// ---------------- K3: nb-weighted sums, direction-split ----------------
// bx < Nv : col-dir, n=bx: S1[n,m,c] = sum_i nb[i,m] x[i,n,c]; + rcs2/ds2 atomics
// bx >= Nv: row-dir, n=bx-Nv: S2[n,m,c] = sum_j nb[j,m] x[n,j,c]
__global__ __launch_bounds__(256) void k_wsum(const float* __restrict__ x) {
    int bx = blockIdx.x, b = blockIdx.y;
    int t = threadIdx.x, c4 = t & 7, sub = t >> 3;
    __shared__ __align__(16) float4 nbl[Nv];
    if (t < Nv) nbl[t] = ((const float4*)(g_nb + (size_t)b * Nv * Mv))[t];
    __syncthreads();
    const float4* xb4 = (const float4*)(x + (size_t)b * Nv * Nv * Cv);
    float4 a[4];
    #pragma unroll
    for (int m = 0; m < 4; m++) a[m] = {0.f,0.f,0.f,0.f};
    __shared__ float red[32][132];
    if (bx < Nv) {
        int n = bx;
        for (int i = sub; i < Nv; i += 32) {
            float4 v = xb4[((size_t)i * Nv + n) * 8 + c4];
            float4 nv = nbl[i];
            a[0].x += nv.x*v.x; a[0].y += nv.x*v.y; a[0].z += nv.x*v.z; a[0].w += nv.x*v.w;
            a[1].x += nv.y*v.x; a[1].y += nv.y*v.y; a[1].z += nv.y*v.z; a[1].w += nv.y*v.w;
            a[2].x += nv.z*v.x; a[2].y += nv.z*v.y; a[2].z += nv.z*v.z; a[2].w += nv.z*v.w;
            a[3].x += nv.w*v.x; a[3].y += nv.w*v.y; a[3].z += nv.w*v.z; a[3].w += nv.w*v.w;
        }
        #pragma unroll
        for (int m = 0; m < 4; m++) {
            red[sub][m*32 + c4*4+0] = a[m].x; red[sub][m*32 + c4*4+1] = a[m].y;
            red[sub][m*32 + c4*4+2] = a[m].z; red[sub][m*32 + c4*4+3] = a[m].w;
        }
        __syncthreads();
        if (t < 128) {
            float s = 0.f;
            #pragma unroll
            for (int k = 0; k < 32; k++) s += red[k][t];
            g_S1[(size_t)(b * Nv + n) * MCv + t] = s;
            int m = t >> 5, c = t & 31;
            float nv = ((const float*)&nbl[n])[m];
            atomicAdd(&g_rcs2[b * MCv + t], nv * s);
            atomicAdd(&g_ds2 [b * MCv + t], nv * nv * g_dgx[(b * Nv + n) * Cv + c]);
        }
    } else {
        int n = bx - Nv;
        for (int j = sub; j < Nv; j += 32) {
            float4 v = xb4[((size_t)n * Nv + j) * 8 + c4];
            float4 nv = nbl[j];
            a[0].x += nv.x*v.x; a[0].y += nv.x*v.y; a[0].z += nv.x*v.z; a[0].w += nv.x*v.w;
            a[1].x += nv.y*v.x; a[1].y += nv.y*v.y; a[1].z += nv.y*v.z; a[1].w += nv.y*v.w;
            a[2].x += nv.z*v.x; a[2].y += nv.z*v.y; a[2].z += nv.z*v.z; a[2].w += nv.z*v.w;
            a[3].x += nv.w*v.x; a[3].y += nv.w*v.y; a[3].z += nv.w*v.z; a[3].w += nv.w*v.w;
        }
        #pragma unroll
        for (int m = 0; m < 4; m++) {
            red[sub][m*32 + c4*4+0] = a[m].x; red[sub][m*32 + c4*4+1] = a[m].y;
            red[sub][m*32 + c4*4+2] = a[m].z; red[sub][m*32 + c4*4+3] = a[m].w;
        }
        __syncthreads();
        if (t < 128) {
            float s = 0.f;
            #pragma unroll
            for (int k = 0; k < 32; k++) s += red[k][t];
            g_S2[(size_t)(b * Nv + n) * MCv + t] = s;
        }
    }
}

// ---------------- K4: per-column additive term, k-split; t0 matvec fused ------
// add[b,n,o] = sum_mc [ nb/N*S1*w1d + nb/N*S2*w1d' + nb^2*dgx*w1d''
//                     + rcs2/N^2*w0d + ds2/N*w0d' ] + biases
__global__ __launch_bounds__(256) void k_add(const float* __restrict__ w1d,
                                             const float* __restrict__ b1d,
                                             const float* __restrict__ b2d,
                                             const float* __restrict__ w0d,
                                             const float* __restrict__ b0d) {
    int b = blockIdx.y, n = blockIdx.x;
    int t = threadIdx.x, o = t & 63, ks = t >> 6;   // ks = wave = m
    __shared__ float red[4][64];
    const float invN = 1.0f / Nv;
    const float invN2 = invN * invN;
    float nv = g_nb[(b * Nv + n) * Mv + ks];
    float f = nv * invN, d2 = nv * nv;
    const float* S1r = g_S1 + (size_t)(b * Nv + n) * MCv + ks * 32;
    const float* S2r = g_S2 + (size_t)(b * Nv + n) * MCv + ks * 32;
    const float* dgr = g_dgx + (size_t)(b * Nv + n) * Cv;
    const float* rcr = g_rcs2 + b * MCv + ks * 32;
    const float* dsr = g_ds2  + b * MCv + ks * 32;
    float acc = 0.f;
    #pragma unroll 8
    for (int c = 0; c < 32; c++) {
        int mc = ks * 32 + c;
        acc += f * S1r[c] * w1d[(size_t)mc * OUTv + o]
             + f * S2r[c] * w1d[(size_t)(MCv + mc) * OUTv + o]
             + d2 * dgr[c] * w1d[(size_t)(2 * MCv + mc) * OUTv + o]
             + invN2 * rcr[c] * w0d[(size_t)mc * OUTv + o]
             + invN  * dsr[c] * w0d[(size_t)(MCv + mc) * OUTv + o];
    }
    red[ks][o] = acc;
    __syncthreads();
    if (t < 64) {
        float v = red[0][t] + red[1][t] + red[2][t] + red[3][t]
                + b1d[t] + b2d[t] + b0d[t];
        g_addv[(size_t)(b * Nv + n) * OUTv + t] = v;
    }
}

// ---------------- K5: main term via MFMA f16 ----------------
// W fragments read straight from g_wfrag (L1/L2-resident 32 KB broadcast tile);
// LDS holds only the Xt/Xb f16 tiles (20 KB) -> ~2x blocks/CU vs staging W in LDS.
#define XPAD 40
__global__ __launch_bounds__(256) void k_main(const float* __restrict__ x,
                                              float* __restrict__ out) {
    int jt = blockIdx.x, i = blockIdx.y, b = blockIdx.z;
    int j0 = jt * 128;
    int t = threadIdx.x;
    int lane = t & 63, w = t >> 6;
    int rowA = lane & 15, quad = lane >> 4;

    __shared__ __align__(16) _Float16 Xt[128 * XPAD];
    __shared__ __align__(16) _Float16 Xb[128 * XPAD];

    {
        const float4* x4 = (const float4*)x;
        #pragma unroll
        for (int r = 0; r < 4; r++) {
            int idx = r * 256 + t;
            int j = idx >> 3, c4 = idx & 7;
            float4 v = x4[((size_t)(b * Nv + i) * Nv + j0 + j) * 8 + c4];
            h4 hv; hv[0] = (_Float16)v.x; hv[1] = (_Float16)v.y;
            hv[2] = (_Float16)v.z; hv[3] = (_Float16)v.w;
            *(h4*)&Xt[j * XPAD + c4 * 4] = hv;
            float4 u = x4[((size_t)(b * Nv + j0 + j) * Nv + i) * 8 + c4];
            h4 hu; hu[0] = (_Float16)u.x; hu[1] = (_Float16)u.y;
            hu[2] = (_Float16)u.z; hu[3] = (_Float16)u.w;
            *(h4*)&Xb[j * XPAD + c4 * 4] = hu;
        }
    }
    int jl1 = w * 32 + rowA, jl2 = jl1 + 16;
    _Float16 e1h[4], e2h[4];
    {
        const float* ni = g_nb + (size_t)(b * Nv + i) * Mv;
        const float* n1 = g_nb + (size_t)(b * Nv + j0 + jl1) * Mv;
        const float* n2 = g_nb + (size_t)(b * Nv + j0 + jl2) * Mv;
        #pragma unroll
        for (int m = 0; m < 4; m++) {
            e1h[m] = (_Float16)(ni[m] * n1[m]);
            e2h[m] = (_Float16)(ni[m] * n2[m]);
        }
    }
    __syncthreads();

    f4 acc[2][4];
    #pragma unroll
    for (int js = 0; js < 2; js++)
        #pragma unroll
        for (int q = 0; q < 4; q++) acc[js][q] = {0.f, 0.f, 0.f, 0.f};

    const h8* Wf = (const h8*)g_wfrag;
    #pragma unroll
    for (int part = 0; part < 2; part++) {
        const _Float16* X = part ? Xb : Xt;
        h8 xv1 = *(const h8*)&X[jl1 * XPAD + quad * 8];
        h8 xv2 = *(const h8*)&X[jl2 * XPAD + quad * 8];
        #pragma unroll
        for (int m = 0; m < 4; m++) {
            h8 a1 = xv1 * e1h[m];
            h8 a2 = xv2 * e2h[m];
            int s = part * 4 + m;
            #pragma unroll
            for (int q = 0; q < 4; q++) {
                h8 bf = Wf[(s * 4 + q) * 64 + lane];
                acc[0][q] = __builtin_amdgcn_mfma_f32_16x16x32_f16(a1, bf, acc[0][q], 0, 0, 0);
                acc[1][q] = __builtin_amdgcn_mfma_f32_16x16x32_f16(a2, bf, acc[1][q], 0, 0, 0);
            }
        }
    }
    #pragma unroll
    for (int js = 0; js < 2; js++) {
        int jbase = j0 + w * 32 + js * 16 + quad * 4;
        #pragma unroll
        for (int q = 0; q < 4; q++) {
            int o = q * 16 + rowA;
            #pragma unroll
            for (int r = 0; r < 4; r++) {
                int j = jbase + r;
                float v = acc[js][q][r] + g_addv[(size_t)(b * Nv + j) * OUTv + o];
                out[(((size_t)(b * Nv + i)) * Nv + j) * OUTv + o] = v;
            }
        }
    }
}

extern "C" void kernel_launch(void* const* d_in, const int* in_sizes, int n_in,
                              void* d_out, int out_size, void* d_ws, size_t ws_size,
                              hipStream_t stream) {
    const float* x     = (const float*)d_in[0];
    const float* w1_nb = (const float*)d_in[1];
    const float* b1_nb = (const float*)d_in[2];
    const float* w0_nb = (const float*)d_in[3];
    const float* b0_nb = (const float*)d_in[4];
    const float* w2d   = (const float*)d_in[5];
    const float* b2d   = (const float*)d_in[6];
    const float* w1d   = (const float*)d_in[7];
    const float* b1d   = (const float*)d_in[8];
    const float* w0d   = (const float*)d_in[9];
    const float* b0d   = (const float*)d_in[10];
    float* out = (float*)d_out;
    (void)d_ws; (void)ws_size;

    hipLaunchKernelGGL(k_contract1, dim3(2 * Nv + 9, Bv), dim3(256), 0, stream, x, w2d);
    hipLaunchKernelGGL(k_neighb, dim3(Bv), dim3(256), 0, stream,
                       w1_nb, b1_nb, w0_nb, b0_nb);
    hipLaunchKernelGGL(k_wsum, dim3(2 * Nv, Bv), dim3(256), 0, stream, x);
    hipLaunchKernelGGL(k_add, dim3(Nv, Bv), dim3(256), 0, stream,
                       w1d, b1d, b2d, w0d, b0d);
    hipLaunchKernelGGL(k_main, dim3(2, Nv, Bv), dim3(256), 0, stream, x, out);
}

// Round 2
// 173.624 us; speedup vs baseline: 1.0996x; 1.0996x over previous
//
#include <hip/hip_runtime.h>
#include <math.h>

#define Bv 4
#define Nv 256
#define Cv 32
#define Mv 4
#define OUTv 64
#define MCv (Mv*Cv)      // 128

typedef _Float16 h8 __attribute__((ext_vector_type(8)));
typedef _Float16 h4 __attribute__((ext_vector_type(4)));
typedef float f4 __attribute__((ext_vector_type(4)));

// ---- static device scratch ----
__device__ __align__(16) float g_rs  [Bv * Nv * Cv];
__device__ __align__(16) float g_cs  [Bv * Nv * Cv];
__device__ __align__(16) float g_dgx [Bv * Nv * Cv];
__device__ __align__(16) float g_nb  [Bv * Nv * Mv];
__device__ __align__(16) float g_S1  [Bv * Nv * MCv];
__device__ __align__(16) float g_S2  [Bv * Nv * MCv];
__device__ __align__(16) float g_rcs2R[8 * Bv * MCv];   // 8 XCD-aligned atomic replicas
__device__ __align__(16) float g_ds2 [Bv * MCv];        // written directly by k_neighb
__device__ __align__(16) float g_addv[Bv * Nv * OUTv];
__device__ __align__(16) _Float16 g_wfrag[8 * 4 * 64 * 8];   // 32 KB

// ---------------- K1: row/col/diag contractions, direction-split --------------
// Absorbs w2d pack (blocks bx >= 2*Nv, blockIdx.y==0) + zeroing of rcs2 replicas.
// bx < Nv : col-dir, n=bx: rs[n,c] = (1/N) sum_i x[i,n,c]; also dgx[n]
// bx >= Nv: row-dir, n=bx-Nv: cs[n,c] = (1/N) sum_j x[n,j,c]
__global__ __launch_bounds__(256) void k_contract1(const float* __restrict__ x,
                                                   const float* __restrict__ w2d) {
    int bx = blockIdx.x, b = blockIdx.y;
    int t = threadIdx.x;
    if (bx >= 2 * Nv) {
        if (b != 0) return;
        int r = bx - 2 * Nv;
        if (r == 8) {                    // zero rcs2 replicas (4096 floats)
            float4 z = {0.f,0.f,0.f,0.f};
            #pragma unroll
            for (int k = 0; k < 4; k++) ((float4*)g_rcs2R)[k * 256 + t] = z;
            return;
        }
        int fi = r * 256 + t;
        int s = fi >> 8, q = (fi >> 6) & 3, lane = fi & 63;
        int k0 = s * 32 + ((lane >> 4) << 3);
        int o = q * 16 + (lane & 15);
        #pragma unroll
        for (int jj = 0; jj < 8; jj++)
            g_wfrag[fi * 8 + jj] = (_Float16)w2d[(size_t)(k0 + jj) * OUTv + o];
        return;
    }
    int c4 = t & 7, sub = t >> 3;   // 32 subs x 8 float4-cols
    const float4* xb4 = (const float4*)(x + (size_t)b * Nv * Nv * Cv);
    __shared__ float red[32][36];
    float4 acc = {0.f,0.f,0.f,0.f};
    if (bx < Nv) {
        int n = bx;
        for (int i = sub; i < Nv; i += 32) {
            float4 v = xb4[((size_t)i * Nv + n) * 8 + c4];
            acc.x += v.x; acc.y += v.y; acc.z += v.z; acc.w += v.w;
        }
        red[sub][c4*4+0] = acc.x; red[sub][c4*4+1] = acc.y;
        red[sub][c4*4+2] = acc.z; red[sub][c4*4+3] = acc.w;
        __syncthreads();
        if (t < 32) {
            float s = 0.f;
            #pragma unroll
            for (int k = 0; k < 32; k++) s += red[k][t];
            g_rs[(b * Nv + n) * Cv + t] = s * (1.0f / Nv);
        }
        if (t < 8) ((float4*)g_dgx)[(b * Nv + n) * 8 + t] = xb4[((size_t)n * Nv + n) * 8 + t];
    } else {
        int n = bx - Nv;
        for (int j = sub; j < Nv; j += 32) {
            float4 v = xb4[((size_t)n * Nv + j) * 8 + c4];
            acc.x += v.x; acc.y += v.y; acc.z += v.z; acc.w += v.w;
        }
        red[sub][c4*4+0] = acc.x; red[sub][c4*4+1] = acc.y;
        red[sub][c4*4+2] = acc.z; red[sub][c4*4+3] = acc.w;
        __syncthreads();
        if (t < 32) {
            float s = 0.f;
            #pragma unroll
            for (int k = 0; k < 32; k++) s += red[k][t];
            g_cs[(b * Nv + n) * Cv + t] = s * (1.0f / Nv);
        }
    }
}

// ---------------- K2: neighborhood linear + sigmoid; also ds2 (separable) -----
__global__ void k_neighb(const float* __restrict__ w1, const float* __restrict__ b1,
                         const float* __restrict__ w0, const float* __restrict__ b0) {
    int b = blockIdx.x, t = threadIdx.x;
    int c = t & 31, sub = t >> 5;
    float ar = 0.f, ad = 0.f;
    for (int n = sub; n < Nv; n += 8) {
        ar += g_rs[(b * Nv + n) * Cv + c];
        ad += g_dgx[(b * Nv + n) * Cv + c];
    }
    __shared__ float red[8][64];
    __shared__ float obj0[64];
    __shared__ float t0nb[4];
    __shared__ float nbs[Nv][4];
    __shared__ float dsred[2][128];
    red[sub][c] = ar;
    red[sub][32 + c] = ad;
    __syncthreads();
    if (t < 64) {
        float s = 0.f;
        #pragma unroll
        for (int k = 0; k < 8; k++) s += red[k][t];
        obj0[t] = s * (1.0f / Nv);
    }
    __syncthreads();
    if (t < 4) {
        float v = b0[t];
        for (int k = 0; k < 2 * Cv; k++) v += obj0[k] * w0[k * Mv + t];
        t0nb[t] = v;
    }
    __syncthreads();
    int n = t;
    float node[4];
    #pragma unroll
    for (int m = 0; m < 4; m++) node[m] = t0nb[m] + b1[m];
    for (int cc = 0; cc < Cv; cc++) {
        float r = g_rs[(b * Nv + n) * Cv + cc];
        float s = g_cs[(b * Nv + n) * Cv + cc];
        float d = g_dgx[(b * Nv + n) * Cv + cc];
        #pragma unroll
        for (int m = 0; m < 4; m++)
            node[m] += r * w1[cc * Mv + m] + s * w1[(Cv + cc) * Mv + m] + d * w1[(2 * Cv + cc) * Mv + m];
    }
    #pragma unroll
    for (int m = 0; m < 4; m++) {
        float sg = 1.0f / (1.0f + expf(-node[m]));
        nbs[t][m] = sg;
        g_nb[(b * Nv + n) * Mv + m] = sg;
    }
    __syncthreads();
    // ds2[mc] = sum_n nb[n,m]^2 * dgx[n,c]   (raw; k_add applies 1/N)
    {
        int mc = t & 127, h = t >> 7;
        int m = mc >> 5, cc = mc & 31;
        float s = 0.f;
        for (int k = 0; k < 128; k++) {
            int nn = h * 128 + k;
            float nv = nbs[nn][m];
            s += nv * nv * g_dgx[(b * Nv + nn) * Cv + cc];
        }
        dsred[h][mc] = s;
    }
    __syncthreads();
    if (t < 128) g_ds2[b * MCv + t] = dsred[0][t] + dsred[1][t];
}

// ---------------- K3: nb-weighted sums, direction-split ----------------
// bx < Nv : col-dir, n=bx: S1[n,m,c] = sum_i nb[i,m] x[i,n,c]; + rcs2 replica atomics
// bx >= Nv: row-dir, n=bx-Nv: S2[n,m,c] = sum_j nb[j,m] x[n,j,c]
__global__ __launch_bounds__(256) void k_wsum(const float* __restrict__ x) {
    int bx = blockIdx.x, b = blockIdx.y;
    int t = threadIdx.x, c4 = t & 7, sub = t >> 3;
    __shared__ __align__(16) float4 nbl[Nv];
    if (t < Nv) nbl[t] = ((const float4*)(g_nb + (size_t)b * Nv * Mv))[t];
    __syncthreads();
    const float4* xb4 = (const float4*)(x + (size_t)b * Nv * Nv * Cv);
    float4 a[4];
    #pragma unroll
    for (int m = 0; m < 4; m++) a[m] = {0.f,0.f,0.f,0.f};
    __shared__ float red[32][132];
    if (bx < Nv) {
        int n = bx;
        for (int i = sub; i < Nv; i += 32) {
            float4 v = xb4[((size_t)i * Nv + n) * 8 + c4];
            float4 nv = nbl[i];
            a[0].x += nv.x*v.x; a[0].y += nv.x*v.y; a[0].z += nv.x*v.z; a[0].w += nv.x*v.w;
            a[1].x += nv.y*v.x; a[1].y += nv.y*v.y; a[1].z += nv.y*v.z; a[1].w += nv.y*v.w;
            a[2].x += nv.z*v.x; a[2].y += nv.z*v.y; a[2].z += nv.z*v.z; a[2].w += nv.z*v.w;
            a[3].x += nv.w*v.x; a[3].y += nv.w*v.y; a[3].z += nv.w*v.z; a[3].w += nv.w*v.w;
        }
        #pragma unroll
        for (int m = 0; m < 4; m++) {
            red[sub][m*32 + c4*4+0] = a[m].x; red[sub][m*32 + c4*4+1] = a[m].y;
            red[sub][m*32 + c4*4+2] = a[m].z; red[sub][m*32 + c4*4+3] = a[m].w;
        }
        __syncthreads();
        if (t < 128) {
            float s = 0.f;
            #pragma unroll
            for (int k = 0; k < 32; k++) s += red[k][t];
            g_S1[(size_t)(b * Nv + n) * MCv + t] = s;
            int m = t >> 5;
            float nv = ((const float*)&nbl[n])[m];
            atomicAdd(&g_rcs2R[(((n & 7) * Bv) + b) * MCv + t], nv * s);
        }
    } else {
        int n = bx - Nv;
        for (int j = sub; j < Nv; j += 32) {
            float4 v = xb4[((size_t)n * Nv + j) * 8 + c4];
            float4 nv = nbl[j];
            a[0].x += nv.x*v.x; a[0].y += nv.x*v.y; a[0].z += nv.x*v.z; a[0].w += nv.x*v.w;
            a[1].x += nv.y*v.x; a[1].y += nv.y*v.y; a[1].z += nv.y*v.z; a[1].w += nv.y*v.w;
            a[2].x += nv.z*v.x; a[2].y += nv.z*v.y; a[2].z += nv.z*v.z; a[2].w += nv.z*v.w;
            a[3].x += nv.w*v.x; a[3].y += nv.w*v.y; a[3].z += nv.w*v.z; a[3].w += nv.w*v.w;
        }
        #pragma unroll
        for (int m = 0; m < 4; m++) {
            red[sub][m*32 + c4*4+0] = a[m].x; red[sub][m*32 + c4*4+1] = a[m].y;
            red[sub][m*32 + c4*4+2] = a[m].z; red[sub][m*32 + c4*4+3] = a[m].w;
        }
        __syncthreads();
        if (t < 128) {
            float s = 0.f;
            #pragma unroll
            for (int k = 0; k < 32; k++) s += red[k][t];
            g_S2[(size_t)(b * Nv + n) * MCv + t] = s;
        }
    }
}

// ---------------- K4: additive term, 2 n per block; t0 matvec fused -----------
// add[b,n,o] = sum_mc [ nb/N*S1*w1d + nb/N*S2*w1d' + nb^2*dgx*w1d''
//                     + rcs2/N^2*w0d + ds2/N*w0d' ] + biases
__global__ __launch_bounds__(256) void k_add(const float* __restrict__ w1d,
                                             const float* __restrict__ b1d,
                                             const float* __restrict__ b2d,
                                             const float* __restrict__ w0d,
                                             const float* __restrict__ b0d) {
    int b = blockIdx.y, n0 = blockIdx.x * 2;
    int t = threadIdx.x, o = t & 63, ks = t >> 6;   // ks = wave = m
    __shared__ float rcl[MCv], dsl[MCv];
    __shared__ float red0[4][64];
    __shared__ float red2[4][2][64];
    if (t < 128) {
        float s = 0.f;
        #pragma unroll
        for (int r = 0; r < 8; r++) s += g_rcs2R[(r * Bv + b) * MCv + t];
        rcl[t] = s;
    } else {
        dsl[t - 128] = g_ds2[b * MCv + (t - 128)];
    }
    __syncthreads();
    const float invN = 1.0f / Nv;
    const float invN2 = invN * invN;
    float nv0 = g_nb[(b * Nv + n0) * Mv + ks];
    float nv1 = g_nb[(b * Nv + n0 + 1) * Mv + ks];
    float f0 = nv0 * invN, d20 = nv0 * nv0;
    float f1 = nv1 * invN, d21 = nv1 * nv1;
    const float* S1a = g_S1 + (size_t)(b * Nv + n0) * MCv + ks * 32;
    const float* S1b = S1a + MCv;
    const float* S2a = g_S2 + (size_t)(b * Nv + n0) * MCv + ks * 32;
    const float* S2b = S2a + MCv;
    const float* dga = g_dgx + (size_t)(b * Nv + n0) * Cv;
    const float* dgb = dga + Cv;
    float acc0v = 0.f, accA = 0.f, accB = 0.f;
    #pragma unroll 8
    for (int cc = 0; cc < 32; cc++) {
        int mc = ks * 32 + cc;
        float w1a = w1d[(size_t)mc * OUTv + o];
        float w1b = w1d[(size_t)(MCv + mc) * OUTv + o];
        float w1c = w1d[(size_t)(2 * MCv + mc) * OUTv + o];
        float w0a = w0d[(size_t)mc * OUTv + o];
        float w0b = w0d[(size_t)(MCv + mc) * OUTv + o];
        acc0v += invN2 * rcl[mc] * w0a + invN * dsl[mc] * w0b;
        accA  += f0 * S1a[cc] * w1a + f0 * S2a[cc] * w1b + d20 * dga[cc] * w1c;
        accB  += f1 * S1b[cc] * w1a + f1 * S2b[cc] * w1b + d21 * dgb[cc] * w1c;
    }
    red0[ks][o] = acc0v;
    red2[ks][0][o] = accA;
    red2[ks][1][o] = accB;
    __syncthreads();
    if (t < 128) {
        int nn = t >> 6, oo = t & 63;
        float t0v = red0[0][oo] + red0[1][oo] + red0[2][oo] + red0[3][oo]
                  + b1d[oo] + b2d[oo] + b0d[oo];
        float v = red2[0][nn][oo] + red2[1][nn][oo] + red2[2][nn][oo] + red2[3][nn][oo] + t0v;
        g_addv[(size_t)(b * Nv + n0 + nn) * OUTv + oo] = v;
    }
}

// ---------------- K5: main term via MFMA f16 (round-0: W staged in LDS) -------
#define XPAD 40
__global__ __launch_bounds__(256) void k_main(const float* __restrict__ x,
                                              float* __restrict__ out) {
    int jt = blockIdx.x, i = blockIdx.y, b = blockIdx.z;
    int j0 = jt * 128;
    int t = threadIdx.x;
    int lane = t & 63, w = t >> 6;
    int rowA = lane & 15, quad = lane >> 4;

    __shared__ __align__(16) _Float16 Wl[8 * 4 * 64 * 8];   // 32 KB
    __shared__ __align__(16) _Float16 Xt[128 * XPAD];
    __shared__ __align__(16) _Float16 Xb[128 * XPAD];

    {
        const float4* src = (const float4*)g_wfrag;
        float4* dst = (float4*)Wl;
        #pragma unroll
        for (int r = 0; r < 8; r++) dst[r * 256 + t] = src[r * 256 + t];
    }
    {
        const float4* x4 = (const float4*)x;
        #pragma unroll
        for (int r = 0; r < 4; r++) {
            int idx = r * 256 + t;
            int j = idx >> 3, c4 = idx & 7;
            float4 v = x4[((size_t)(b * Nv + i) * Nv + j0 + j) * 8 + c4];
            h4 hv; hv[0] = (_Float16)v.x; hv[1] = (_Float16)v.y;
            hv[2] = (_Float16)v.z; hv[3] = (_Float16)v.w;
            *(h4*)&Xt[j * XPAD + c4 * 4] = hv;
            float4 u = x4[((size_t)(b * Nv + j0 + j) * Nv + i) * 8 + c4];
            h4 hu; hu[0] = (_Float16)u.x; hu[1] = (_Float16)u.y;
            hu[2] = (_Float16)u.z; hu[3] = (_Float16)u.w;
            *(h4*)&Xb[j * XPAD + c4 * 4] = hu;
        }
    }
    int jl1 = w * 32 + rowA, jl2 = jl1 + 16;
    _Float16 e1h[4], e2h[4];
    {
        const float* ni = g_nb + (size_t)(b * Nv + i) * Mv;
        const float* n1 = g_nb + (size_t)(b * Nv + j0 + jl1) * Mv;
        const float* n2 = g_nb + (size_t)(b * Nv + j0 + jl2) * Mv;
        #pragma unroll
        for (int m = 0; m < 4; m++) {
            e1h[m] = (_Float16)(ni[m] * n1[m]);
            e2h[m] = (_Float16)(ni[m] * n2[m]);
        }
    }
    __syncthreads();

    f4 acc[2][4];
    #pragma unroll
    for (int js = 0; js < 2; js++)
        #pragma unroll
        for (int q = 0; q < 4; q++) acc[js][q] = {0.f, 0.f, 0.f, 0.f};

    const h8* Wf = (const h8*)Wl;
    #pragma unroll
    for (int part = 0; part < 2; part++) {
        const _Float16* X = part ? Xb : Xt;
        h8 xv1 = *(const h8*)&X[jl1 * XPAD + quad * 8];
        h8 xv2 = *(const h8*)&X[jl2 * XPAD + quad * 8];
        #pragma unroll
        for (int m = 0; m < 4; m++) {
            h8 a1 = xv1 * e1h[m];
            h8 a2 = xv2 * e2h[m];
            int s = part * 4 + m;
            #pragma unroll
            for (int q = 0; q < 4; q++) {
                h8 bf = Wf[(s * 4 + q) * 64 + lane];
                acc[0][q] = __builtin_amdgcn_mfma_f32_16x16x32_f16(a1, bf, acc[0][q], 0, 0, 0);
                acc[1][q] = __builtin_amdgcn_mfma_f32_16x16x32_f16(a2, bf, acc[1][q], 0, 0, 0);
            }
        }
    }
    #pragma unroll
    for (int js = 0; js < 2; js++) {
        int jbase = j0 + w * 32 + js * 16 + quad * 4;
        #pragma unroll
        for (int q = 0; q < 4; q++) {
            int o = q * 16 + rowA;
            #pragma unroll
            for (int r = 0; r < 4; r++) {
                int j = jbase + r;
                float v = acc[js][q][r] + g_addv[(size_t)(b * Nv + j) * OUTv + o];
                out[(((size_t)(b * Nv + i)) * Nv + j) * OUTv + o] = v;
            }
        }
    }
}

extern "C" void kernel_launch(void* const* d_in, const int* in_sizes, int n_in,
                              void* d_out, int out_size, void* d_ws, size_t ws_size,
                              hipStream_t stream) {
    const float* x     = (const float*)d_in[0];
    const float* w1_nb = (const float*)d_in[1];
    const float* b1_nb = (const float*)d_in[2];
    const float* w0_nb = (const float*)d_in[3];
    const float* b0_nb = (const float*)d_in[4];
    const float* w2d   = (const float*)d_in[5];
    const float* b2d   = (const float*)d_in[6];
    const float* w1d   = (const float*)d_in[7];
    const float* b1d   = (const float*)d_in[8];
    const float* w0d   = (const float*)d_in[9];
    const float* b0d   = (const float*)d_in[10];
    float* out = (float*)d_out;
    (void)d_ws; (void)ws_size;

    hipLaunchKernelGGL(k_contract1, dim3(2 * Nv + 9, Bv), dim3(256), 0, stream, x, w2d);
    hipLaunchKernelGGL(k_neighb, dim3(Bv), dim3(256), 0, stream,
                       w1_nb, b1_nb, w0_nb, b0_nb);
    hipLaunchKernelGGL(k_wsum, dim3(2 * Nv, Bv), dim3(256), 0, stream, x);
    hipLaunchKernelGGL(k_add, dim3(Nv / 2, Bv), dim3(256), 0, stream,
                       w1d, b1d, b2d, w0d, b0d);
    hipLaunchKernelGGL(k_main, dim3(2, Nv, Bv), dim3(256), 0, stream, x, out);
}

// Round 3
// 169.421 us; speedup vs baseline: 1.1268x; 1.0248x over previous
//
#include <hip/hip_runtime.h>
#include <math.h>

#define Bv 4
#define Nv 256
#define Cv 32
#define Mv 4
#define OUTv 64
#define MCv (Mv*Cv)      // 128

typedef _Float16 h8 __attribute__((ext_vector_type(8)));
typedef _Float16 h4 __attribute__((ext_vector_type(4)));
typedef float f4 __attribute__((ext_vector_type(4)));

// ---- static device scratch ----
__device__ __align__(16) float g_rs  [Bv * Nv * Cv];
__device__ __align__(16) float g_cs  [Bv * Nv * Cv];
__device__ __align__(16) float g_dgx [Bv * Nv * Cv];
__device__ __align__(16) float g_nb  [Bv * Nv * Mv];
__device__ __align__(16) float g_S1  [Bv * Nv * MCv];
__device__ __align__(16) float g_S2  [Bv * Nv * MCv];
__device__ __align__(16) float g_rcs2R[8 * Bv * MCv];   // 8 XCD-aligned atomic replicas
__device__ __align__(16) float g_ds2R [8 * Bv * MCv];   // 8 XCD-aligned atomic replicas
__device__ __align__(16) float g_addv[Bv * Nv * OUTv];
__device__ __align__(16) _Float16 g_wfrag[8 * 4 * 64 * 8];   // 32 KB

// ---------------- K1: row/col/diag contractions, direction-split --------------
// Absorbs w2d pack (blocks bx >= 2*Nv, blockIdx.y==0) + zeroing of replicas.
__global__ __launch_bounds__(256) void k_contract1(const float* __restrict__ x,
                                                   const float* __restrict__ w2d) {
    int bx = blockIdx.x, b = blockIdx.y;
    int t = threadIdx.x;
    if (bx >= 2 * Nv) {
        if (b != 0) return;
        int r = bx - 2 * Nv;
        if (r == 8) {                    // zero rcs2/ds2 replicas (2 x 4096 floats)
            float4 z = {0.f,0.f,0.f,0.f};
            #pragma unroll
            for (int k = 0; k < 4; k++) {
                ((float4*)g_rcs2R)[k * 256 + t] = z;
                ((float4*)g_ds2R )[k * 256 + t] = z;
            }
            return;
        }
        int fi = r * 256 + t;
        int s = fi >> 8, q = (fi >> 6) & 3, lane = fi & 63;
        int k0 = s * 32 + ((lane >> 4) << 3);
        int o = q * 16 + (lane & 15);
        #pragma unroll
        for (int jj = 0; jj < 8; jj++)
            g_wfrag[fi * 8 + jj] = (_Float16)w2d[(size_t)(k0 + jj) * OUTv + o];
        return;
    }
    int c4 = t & 7, sub = t >> 3;   // 32 subs x 8 float4-cols
    const float4* xb4 = (const float4*)(x + (size_t)b * Nv * Nv * Cv);
    __shared__ float red[32][36];
    float4 acc = {0.f,0.f,0.f,0.f};
    if (bx < Nv) {
        int n = bx;
        for (int i = sub; i < Nv; i += 32) {
            float4 v = xb4[((size_t)i * Nv + n) * 8 + c4];
            acc.x += v.x; acc.y += v.y; acc.z += v.z; acc.w += v.w;
        }
        red[sub][c4*4+0] = acc.x; red[sub][c4*4+1] = acc.y;
        red[sub][c4*4+2] = acc.z; red[sub][c4*4+3] = acc.w;
        __syncthreads();
        if (t < 32) {
            float s = 0.f;
            #pragma unroll
            for (int k = 0; k < 32; k++) s += red[k][t];
            g_rs[(b * Nv + n) * Cv + t] = s * (1.0f / Nv);
        }
        if (t < 8) ((float4*)g_dgx)[(b * Nv + n) * 8 + t] = xb4[((size_t)n * Nv + n) * 8 + t];
    } else {
        int n = bx - Nv;
        for (int j = sub; j < Nv; j += 32) {
            float4 v = xb4[((size_t)n * Nv + j) * 8 + c4];
            acc.x += v.x; acc.y += v.y; acc.z += v.z; acc.w += v.w;
        }
        red[sub][c4*4+0] = acc.x; red[sub][c4*4+1] = acc.y;
        red[sub][c4*4+2] = acc.z; red[sub][c4*4+3] = acc.w;
        __syncthreads();
        if (t < 32) {
            float s = 0.f;
            #pragma unroll
            for (int k = 0; k < 32; k++) s += red[k][t];
            g_cs[(b * Nv + n) * Cv + t] = s * (1.0f / Nv);
        }
    }
}

// ---------------- K2: neighborhood linear + sigmoid (light form) --------------
__global__ void k_neighb(const float* __restrict__ w1, const float* __restrict__ b1,
                         const float* __restrict__ w0, const float* __restrict__ b0) {
    int b = blockIdx.x, t = threadIdx.x;
    int c = t & 31, sub = t >> 5;
    float ar = 0.f, ad = 0.f;
    for (int n = sub; n < Nv; n += 8) {
        ar += g_rs[(b * Nv + n) * Cv + c];
        ad += g_dgx[(b * Nv + n) * Cv + c];
    }
    __shared__ float red[8][64];
    __shared__ float obj0[64];
    __shared__ float t0nb[4];
    red[sub][c] = ar;
    red[sub][32 + c] = ad;
    __syncthreads();
    if (t < 64) {
        float s = 0.f;
        #pragma unroll
        for (int k = 0; k < 8; k++) s += red[k][t];
        obj0[t] = s * (1.0f / Nv);
    }
    __syncthreads();
    if (t < 4) {
        float v = b0[t];
        for (int k = 0; k < 2 * Cv; k++) v += obj0[k] * w0[k * Mv + t];
        t0nb[t] = v;
    }
    __syncthreads();
    int n = t;
    float node[4];
    #pragma unroll
    for (int m = 0; m < 4; m++) node[m] = t0nb[m] + b1[m];
    for (int cc = 0; cc < Cv; cc++) {
        float r = g_rs[(b * Nv + n) * Cv + cc];
        float s = g_cs[(b * Nv + n) * Cv + cc];
        float d = g_dgx[(b * Nv + n) * Cv + cc];
        #pragma unroll
        for (int m = 0; m < 4; m++)
            node[m] += r * w1[cc * Mv + m] + s * w1[(Cv + cc) * Mv + m] + d * w1[(2 * Cv + cc) * Mv + m];
    }
    #pragma unroll
    for (int m = 0; m < 4; m++)
        g_nb[(b * Nv + n) * Mv + m] = 1.0f / (1.0f + expf(-node[m]));
}

// ---------------- K3: nb-weighted sums, direction-split ----------------
// bx < Nv : col-dir, n=bx: S1[n,m,c] = sum_i nb[i,m] x[i,n,c];
//            + rcs2/ds2 via 8-replica XCD-aligned atomics
// bx >= Nv: row-dir, n=bx-Nv: S2[n,m,c] = sum_j nb[j,m] x[n,j,c]
__global__ __launch_bounds__(256) void k_wsum(const float* __restrict__ x) {
    int bx = blockIdx.x, b = blockIdx.y;
    int t = threadIdx.x, c4 = t & 7, sub = t >> 3;
    __shared__ __align__(16) float4 nbl[Nv];
    if (t < Nv) nbl[t] = ((const float4*)(g_nb + (size_t)b * Nv * Mv))[t];
    __syncthreads();
    const float4* xb4 = (const float4*)(x + (size_t)b * Nv * Nv * Cv);
    float4 a[4];
    #pragma unroll
    for (int m = 0; m < 4; m++) a[m] = {0.f,0.f,0.f,0.f};
    __shared__ float red[32][132];
    if (bx < Nv) {
        int n = bx;
        for (int i = sub; i < Nv; i += 32) {
            float4 v = xb4[((size_t)i * Nv + n) * 8 + c4];
            float4 nv = nbl[i];
            a[0].x += nv.x*v.x; a[0].y += nv.x*v.y; a[0].z += nv.x*v.z; a[0].w += nv.x*v.w;
            a[1].x += nv.y*v.x; a[1].y += nv.y*v.y; a[1].z += nv.y*v.z; a[1].w += nv.y*v.w;
            a[2].x += nv.z*v.x; a[2].y += nv.z*v.y; a[2].z += nv.z*v.z; a[2].w += nv.z*v.w;
            a[3].x += nv.w*v.x; a[3].y += nv.w*v.y; a[3].z += nv.w*v.z; a[3].w += nv.w*v.w;
        }
        #pragma unroll
        for (int m = 0; m < 4; m++) {
            red[sub][m*32 + c4*4+0] = a[m].x; red[sub][m*32 + c4*4+1] = a[m].y;
            red[sub][m*32 + c4*4+2] = a[m].z; red[sub][m*32 + c4*4+3] = a[m].w;
        }
        __syncthreads();
        if (t < 128) {
            float s = 0.f;
            #pragma unroll
            for (int k = 0; k < 32; k++) s += red[k][t];
            g_S1[(size_t)(b * Nv + n) * MCv + t] = s;
            int m = t >> 5, c = t & 31;
            float nv = ((const float*)&nbl[n])[m];
            int rep = ((n & 7) * Bv + b) * MCv + t;
            atomicAdd(&g_rcs2R[rep], nv * s);
            atomicAdd(&g_ds2R [rep], nv * nv * g_dgx[(b * Nv + n) * Cv + c]);
        }
    } else {
        int n = bx - Nv;
        for (int j = sub; j < Nv; j += 32) {
            float4 v = xb4[((size_t)n * Nv + j) * 8 + c4];
            float4 nv = nbl[j];
            a[0].x += nv.x*v.x; a[0].y += nv.x*v.y; a[0].z += nv.x*v.z; a[0].w += nv.x*v.w;
            a[1].x += nv.y*v.x; a[1].y += nv.y*v.y; a[1].z += nv.y*v.z; a[1].w += nv.y*v.w;
            a[2].x += nv.z*v.x; a[2].y += nv.z*v.y; a[2].z += nv.z*v.z; a[2].w += nv.z*v.w;
            a[3].x += nv.w*v.x; a[3].y += nv.w*v.y; a[3].z += nv.w*v.z; a[3].w += nv.w*v.w;
        }
        #pragma unroll
        for (int m = 0; m < 4; m++) {
            red[sub][m*32 + c4*4+0] = a[m].x; red[sub][m*32 + c4*4+1] = a[m].y;
            red[sub][m*32 + c4*4+2] = a[m].z; red[sub][m*32 + c4*4+3] = a[m].w;
        }
        __syncthreads();
        if (t < 128) {
            float s = 0.f;
            #pragma unroll
            for (int k = 0; k < 32; k++) s += red[k][t];
            g_S2[(size_t)(b * Nv + n) * MCv + t] = s;
        }
    }
}

// ---------------- K4: additive term, 2 n per block; t0 matvec fused -----------
__global__ __launch_bounds__(256) void k_add(const float* __restrict__ w1d,
                                             const float* __restrict__ b1d,
                                             const float* __restrict__ b2d,
                                             const float* __restrict__ w0d,
                                             const float* __restrict__ b0d) {
    int b = blockIdx.y, n0 = blockIdx.x * 2;
    int t = threadIdx.x, o = t & 63, ks = t >> 6;   // ks = wave = m
    __shared__ float rcl[MCv], dsl[MCv];
    __shared__ float red0[4][64];
    __shared__ float red2[4][2][64];
    if (t < 128) {
        float s = 0.f;
        #pragma unroll
        for (int r = 0; r < 8; r++) s += g_rcs2R[(r * Bv + b) * MCv + t];
        rcl[t] = s;
    } else {
        int tt = t - 128;
        float s = 0.f;
        #pragma unroll
        for (int r = 0; r < 8; r++) s += g_ds2R[(r * Bv + b) * MCv + tt];
        dsl[tt] = s;
    }
    __syncthreads();
    const float invN = 1.0f / Nv;
    const float invN2 = invN * invN;
    float nv0 = g_nb[(b * Nv + n0) * Mv + ks];
    float nv1 = g_nb[(b * Nv + n0 + 1) * Mv + ks];
    float f0 = nv0 * invN, d20 = nv0 * nv0;
    float f1 = nv1 * invN, d21 = nv1 * nv1;
    const float* S1a = g_S1 + (size_t)(b * Nv + n0) * MCv + ks * 32;
    const float* S1b = S1a + MCv;
    const float* S2a = g_S2 + (size_t)(b * Nv + n0) * MCv + ks * 32;
    const float* S2b = S2a + MCv;
    const float* dga = g_dgx + (size_t)(b * Nv + n0) * Cv;
    const float* dgb = dga + Cv;
    float acc0v = 0.f, accA = 0.f, accB = 0.f;
    #pragma unroll 8
    for (int cc = 0; cc < 32; cc++) {
        int mc = ks * 32 + cc;
        float w1a = w1d[(size_t)mc * OUTv + o];
        float w1b = w1d[(size_t)(MCv + mc) * OUTv + o];
        float w1c = w1d[(size_t)(2 * MCv + mc) * OUTv + o];
        float w0a = w0d[(size_t)mc * OUTv + o];
        float w0b = w0d[(size_t)(MCv + mc) * OUTv + o];
        acc0v += invN2 * rcl[mc] * w0a + invN * dsl[mc] * w0b;
        accA  += f0 * S1a[cc] * w1a + f0 * S2a[cc] * w1b + d20 * dga[cc] * w1c;
        accB  += f1 * S1b[cc] * w1a + f1 * S2b[cc] * w1b + d21 * dgb[cc] * w1c;
    }
    red0[ks][o] = acc0v;
    red2[ks][0][o] = accA;
    red2[ks][1][o] = accB;
    __syncthreads();
    if (t < 128) {
        int nn = t >> 6, oo = t & 63;
        float t0v = red0[0][oo] + red0[1][oo] + red0[2][oo] + red0[3][oo]
                  + b1d[oo] + b2d[oo] + b0d[oo];
        float v = red2[0][nn][oo] + red2[1][nn][oo] + red2[2][nn][oo] + red2[3][nn][oo] + t0v;
        g_addv[(size_t)(b * Nv + n0 + nn) * OUTv + oo] = v;
    }
}

// ---------------- K5: main term via MFMA f16, 2 output rows per block ---------
// Each W fragment ds_read now feeds 4 MFMAs (2 j-slices x 2 i-rows) -> the LDS
// read pipe (previous bottleneck: 144 b128/block vs 1240cyc MFMA) drops below
// the MFMA pipe. LDS 72 KB -> 2 blocks/CU (8 waves).
#define XPAD 40
__global__ __launch_bounds__(256) void k_main(const float* __restrict__ x,
                                              float* __restrict__ out) {
    int jt = blockIdx.x, ip = blockIdx.y, b = blockIdx.z;
    int i0 = ip * 2, i1 = i0 + 1;
    int j0 = jt * 128;
    int t = threadIdx.x;
    int lane = t & 63, w = t >> 6;
    int rowA = lane & 15, quad = lane >> 4;

    __shared__ __align__(16) _Float16 Wl[8 * 4 * 64 * 8];   // 32 KB
    __shared__ __align__(16) _Float16 Xt0[128 * XPAD];      // 10 KB each
    __shared__ __align__(16) _Float16 Xb0[128 * XPAD];
    __shared__ __align__(16) _Float16 Xt1[128 * XPAD];
    __shared__ __align__(16) _Float16 Xb1[128 * XPAD];

    {
        const float4* src = (const float4*)g_wfrag;
        float4* dst = (float4*)Wl;
        #pragma unroll
        for (int r = 0; r < 8; r++) dst[r * 256 + t] = src[r * 256 + t];
    }
    {
        const float4* x4 = (const float4*)x;
        #pragma unroll
        for (int r = 0; r < 4; r++) {
            int idx = r * 256 + t;
            int j = idx >> 3, c4 = idx & 7;
            float4 v0 = x4[((size_t)(b * Nv + i0) * Nv + j0 + j) * 8 + c4];
            float4 v1 = x4[((size_t)(b * Nv + i1) * Nv + j0 + j) * 8 + c4];
            float4 u0 = x4[((size_t)(b * Nv + j0 + j) * Nv + i0) * 8 + c4];
            float4 u1 = x4[((size_t)(b * Nv + j0 + j) * Nv + i1) * 8 + c4];
            h4 h0; h0[0] = (_Float16)v0.x; h0[1] = (_Float16)v0.y;
            h0[2] = (_Float16)v0.z; h0[3] = (_Float16)v0.w;
            *(h4*)&Xt0[j * XPAD + c4 * 4] = h0;
            h4 h1; h1[0] = (_Float16)v1.x; h1[1] = (_Float16)v1.y;
            h1[2] = (_Float16)v1.z; h1[3] = (_Float16)v1.w;
            *(h4*)&Xt1[j * XPAD + c4 * 4] = h1;
            h4 g0; g0[0] = (_Float16)u0.x; g0[1] = (_Float16)u0.y;
            g0[2] = (_Float16)u0.z; g0[3] = (_Float16)u0.w;
            *(h4*)&Xb0[j * XPAD + c4 * 4] = g0;
            h4 g1; g1[0] = (_Float16)u1.x; g1[1] = (_Float16)u1.y;
            g1[2] = (_Float16)u1.z; g1[3] = (_Float16)u1.w;
            *(h4*)&Xb1[j * XPAD + c4 * 4] = g1;
        }
    }
    int jl1 = w * 32 + rowA, jl2 = jl1 + 16;
    _Float16 e1h0[4], e2h0[4], e1h1[4], e2h1[4];
    {
        const float* ni0 = g_nb + (size_t)(b * Nv + i0) * Mv;
        const float* ni1 = g_nb + (size_t)(b * Nv + i1) * Mv;
        const float* n1 = g_nb + (size_t)(b * Nv + j0 + jl1) * Mv;
        const float* n2 = g_nb + (size_t)(b * Nv + j0 + jl2) * Mv;
        #pragma unroll
        for (int m = 0; m < 4; m++) {
            e1h0[m] = (_Float16)(ni0[m] * n1[m]);
            e2h0[m] = (_Float16)(ni0[m] * n2[m]);
            e1h1[m] = (_Float16)(ni1[m] * n1[m]);
            e2h1[m] = (_Float16)(ni1[m] * n2[m]);
        }
    }
    __syncthreads();

    f4 acc[2][2][4];   // [i][js][q]
    #pragma unroll
    for (int ii = 0; ii < 2; ii++)
        #pragma unroll
        for (int js = 0; js < 2; js++)
            #pragma unroll
            for (int q = 0; q < 4; q++) acc[ii][js][q] = {0.f, 0.f, 0.f, 0.f};

    const h8* Wf = (const h8*)Wl;
    #pragma unroll
    for (int part = 0; part < 2; part++) {
        const _Float16* X0 = part ? Xb0 : Xt0;
        const _Float16* X1 = part ? Xb1 : Xt1;
        h8 xv1_0 = *(const h8*)&X0[jl1 * XPAD + quad * 8];
        h8 xv2_0 = *(const h8*)&X0[jl2 * XPAD + quad * 8];
        h8 xv1_1 = *(const h8*)&X1[jl1 * XPAD + quad * 8];
        h8 xv2_1 = *(const h8*)&X1[jl2 * XPAD + quad * 8];
        #pragma unroll
        for (int m = 0; m < 4; m++) {
            h8 a1_0 = xv1_0 * e1h0[m];
            h8 a2_0 = xv2_0 * e2h0[m];
            h8 a1_1 = xv1_1 * e1h1[m];
            h8 a2_1 = xv2_1 * e2h1[m];
            int s = part * 4 + m;
            #pragma unroll
            for (int q = 0; q < 4; q++) {
                h8 bf = Wf[(s * 4 + q) * 64 + lane];
                acc[0][0][q] = __builtin_amdgcn_mfma_f32_16x16x32_f16(a1_0, bf, acc[0][0][q], 0, 0, 0);
                acc[0][1][q] = __builtin_amdgcn_mfma_f32_16x16x32_f16(a2_0, bf, acc[0][1][q], 0, 0, 0);
                acc[1][0][q] = __builtin_amdgcn_mfma_f32_16x16x32_f16(a1_1, bf, acc[1][0][q], 0, 0, 0);
                acc[1][1][q] = __builtin_amdgcn_mfma_f32_16x16x32_f16(a2_1, bf, acc[1][1][q], 0, 0, 0);
            }
        }
    }
    #pragma unroll
    for (int js = 0; js < 2; js++) {
        int jbase = j0 + w * 32 + js * 16 + quad * 4;
        #pragma unroll
        for (int q = 0; q < 4; q++) {
            int o = q * 16 + rowA;
            #pragma unroll
            for (int r = 0; r < 4; r++) {
                int j = jbase + r;
                float av = g_addv[(size_t)(b * Nv + j) * OUTv + o];
                out[(((size_t)(b * Nv + i0)) * Nv + j) * OUTv + o] = acc[0][js][q][r] + av;
                out[(((size_t)(b * Nv + i1)) * Nv + j) * OUTv + o] = acc[1][js][q][r] + av;
            }
        }
    }
}

extern "C" void kernel_launch(void* const* d_in, const int* in_sizes, int n_in,
                              void* d_out, int out_size, void* d_ws, size_t ws_size,
                              hipStream_t stream) {
    const float* x     = (const float*)d_in[0];
    const float* w1_nb = (const float*)d_in[1];
    const float* b1_nb = (const float*)d_in[2];
    const float* w0_nb = (const float*)d_in[3];
    const float* b0_nb = (const float*)d_in[4];
    const float* w2d   = (const float*)d_in[5];
    const float* b2d   = (const float*)d_in[6];
    const float* w1d   = (const float*)d_in[7];
    const float* b1d   = (const float*)d_in[8];
    const float* w0d   = (const float*)d_in[9];
    const float* b0d   = (const float*)d_in[10];
    float* out = (float*)d_out;
    (void)d_ws; (void)ws_size;

    hipLaunchKernelGGL(k_contract1, dim3(2 * Nv + 9, Bv), dim3(256), 0, stream, x, w2d);
    hipLaunchKernelGGL(k_neighb, dim3(Bv), dim3(256), 0, stream,
                       w1_nb, b1_nb, w0_nb, b0_nb);
    hipLaunchKernelGGL(k_wsum, dim3(2 * Nv, Bv), dim3(256), 0, stream, x);
    hipLaunchKernelGGL(k_add, dim3(Nv / 2, Bv), dim3(256), 0, stream,
                       w1d, b1d, b2d, w0d, b0d);
    hipLaunchKernelGGL(k_main, dim3(2, Nv / 2, Bv), dim3(256), 0, stream, x, out);
}